// Round 1
// baseline (189.072 us; speedup 1.0000x reference)
//
#include <hip/hip_runtime.h>
#include <math.h>

#define Nn 6144
#define FIN 128
#define DMID 128
#define DHID 64
#define NH 4
#define NG 12
#define NB 512
#define ALPHA 0.2f
#define EPSV 1e-9f

__device__ __forceinline__ float leaky(float x){ return x > 0.f ? x : ALPHA*x; }
__device__ __forceinline__ float rdlane(float v, int l){
  return __uint_as_float(__builtin_amdgcn_readlane(__float_as_uint(v), l));
}
__device__ __forceinline__ float wave_sum(float v){
  #pragma unroll
  for (int off=32; off; off>>=1) v += __shfl_xor(v, off);
  return v;
}

// h = relu(x @ Wv + bv), 8 rows per block, 128 threads
__global__ void k_fc1(const float* __restrict__ x, const float* __restrict__ Wv,
                      const float* __restrict__ bv, float* __restrict__ h){
  int i0 = blockIdx.x*8;
  int d = threadIdx.x;
  __shared__ float xs[8][FIN];
  for (int idx=d; idx<8*FIN; idx+=128) xs[idx>>7][idx&127] = x[(size_t)i0*FIN + idx];
  __syncthreads();
  float bvv = bv[d];
  float acc[8];
  #pragma unroll
  for (int r=0;r<8;++r) acc[r]=bvv;
  for (int k=0;k<FIN;++k){
    float wv = Wv[k*DMID + d];
    #pragma unroll
    for (int r=0;r<8;++r) acc[r] += xs[r][k]*wv;
  }
  #pragma unroll
  for (int r=0;r<8;++r) h[(size_t)(i0+r)*DMID + d] = fmaxf(acc[r], 0.f);
}

// ft0 = h @ W0cat  ([6144,256], head-major cols), + per-head a1/a2 dots
// 8 rows per block, 256 threads (wave == head)
__global__ void k_ft0(const float* __restrict__ h, const float* __restrict__ W0,
                      const float* __restrict__ al0, const float* __restrict__ ar0,
                      float* __restrict__ ft0, float* __restrict__ a1arr, float* __restrict__ a2arr){
  int i0 = blockIdx.x*8;
  int t = threadIdx.x;
  int hd = t>>6, d = t&63;
  __shared__ float hs[8][DMID];
  for (int idx=t; idx<8*DMID; idx+=256) hs[idx>>7][idx&127] = h[(size_t)i0*DMID + idx];
  __syncthreads();
  float acc[8]={0,0,0,0,0,0,0,0};
  const float* wp = W0 + (size_t)hd*(DMID*DHID) + d;
  for (int k=0;k<DMID;++k){
    float wval = wp[(size_t)k*DHID];
    #pragma unroll
    for (int r=0;r<8;++r) acc[r] += hs[r][k]*wval;
  }
  float alv = al0[hd*DHID+d], arv = ar0[hd*DHID+d];
  #pragma unroll
  for (int r=0;r<8;++r){
    ft0[(size_t)(i0+r)*(NH*DHID) + t] = acc[r];
    float s1 = wave_sum(acc[r]*alv);
    float s2 = wave_sum(acc[r]*arv);
    if (d==0){ a1arr[hd*Nn + i0+r] = s1; a2arr[hd*Nn + i0+r] = s2; }
  }
}

// per-segment max reduce: out[seg] = max(in[seg*count : (seg+1)*count])
__global__ void k_max(const float* __restrict__ in, float* __restrict__ out, int count){
  int seg = blockIdx.x;
  const float* p = in + (size_t)seg*count;
  float mval = -INFINITY;
  for (int i=threadIdx.x; i<count; i+=blockDim.x) mval = fmaxf(mval, p[i]);
  #pragma unroll
  for (int off=32; off; off>>=1) mval = fmaxf(mval, __shfl_xor(mval, off));
  __shared__ float sm[4];
  if ((threadIdx.x&63)==0) sm[threadIdx.x>>6] = mval;
  __syncthreads();
  if (threadIdx.x==0) out[seg] = fmaxf(fmaxf(sm[0],sm[1]), fmaxf(sm[2],sm[3]));
}

// attention layer0: block = 8 rows x 4 heads (wave=head), out h1 [6144,256]
__global__ void k_attn0(const float* __restrict__ ft0, const float* __restrict__ a1arr,
                        const float* __restrict__ a2arr, const float* __restrict__ maxa2,
                        const float* __restrict__ mask, float* __restrict__ h1){
  int i0 = blockIdx.x*8;
  int g = i0 / NB;
  int hd = threadIdx.x >> 6;
  int lane = threadIdx.x & 63;
  float mx = maxa2[hd];
  float a1v[8], m[8], acc[8], dsum[8];
  #pragma unroll
  for (int r=0;r<8;++r){
    a1v[r]=a1arr[hd*Nn + i0+r]; m[r]=leaky(a1v[r]+mx); acc[r]=0.f; dsum[r]=0.f;
  }
  int jbase = g*NB;
  for (int c=0;c<8;++c){
    int j = jbase + c*64 + lane;
    float a2v = a2arr[hd*Nn + j];
    float w[8];
    #pragma unroll
    for (int r=0;r<8;++r){
      float val = __expf(leaky(a1v[r]+a2v)-m[r]) * mask[(size_t)(i0+r)*Nn + j];
      w[r]=val; dsum[r]+=val;
    }
    const float* fp = ft0 + (size_t)(jbase + c*64)*(NH*DHID) + hd*DHID + lane;
    #pragma unroll 16
    for (int jj=0;jj<64;++jj){
      float fv = fp[(size_t)jj*(NH*DHID)];
      #pragma unroll
      for (int r=0;r<8;++r) acc[r] += rdlane(w[r], jj)*fv;
    }
  }
  #pragma unroll
  for (int r=0;r<8;++r){
    float denom = wave_sum(dsum[r]) + EPSV;
    float o = acc[r]/denom;
    o = o>0.f ? o : __expf(o)-1.f;
    h1[(size_t)(i0+r)*(NH*DHID) + hd*DHID + lane] = o;
  }
}

// ftf = h1 @ Wf  ([6144,128]), 8 rows per block, 128 threads
__global__ void k_fcf(const float* __restrict__ h1, const float* __restrict__ Wf,
                      float* __restrict__ ftf){
  int i0 = blockIdx.x*8;
  int d = threadIdx.x;
  __shared__ float hs[8][NH*DHID];
  for (int idx=d; idx<8*NH*DHID; idx+=128) hs[idx>>8][idx&255] = h1[(size_t)i0*(NH*DHID) + idx];
  __syncthreads();
  float acc[8]={0,0,0,0,0,0,0,0};
  for (int k=0;k<NH*DHID;++k){
    float wv = Wf[(size_t)k*DMID + d];
    #pragma unroll
    for (int r=0;r<8;++r) acc[r] += hs[r][k]*wv;
  }
  #pragma unroll
  for (int r=0;r<8;++r) ftf[(size_t)(i0+r)*DMID + d] = acc[r];
}

// a1f/a2f dots for final layer: 1 wave per node
__global__ void k_dotsf(const float* __restrict__ ftf, const float* __restrict__ alf,
                        const float* __restrict__ arf, float* __restrict__ a1f, float* __restrict__ a2f){
  int n = blockIdx.x*4 + (threadIdx.x>>6);
  int lane = threadIdx.x&63;
  float v0 = ftf[(size_t)n*DMID + lane], v1 = ftf[(size_t)n*DMID + 64 + lane];
  float s1 = wave_sum(v0*alf[lane] + v1*alf[64+lane]);
  float s2 = wave_sum(v0*arf[lane] + v1*arf[64+lane]);
  if (lane==0){ a1f[n]=s1; a2f[n]=s2; }
}

// final attention layer: block = 8 rows, 2 waves split the j-range, out h2 [6144,128]
__global__ void k_attnf(const float* __restrict__ ftf, const float* __restrict__ a1f,
                        const float* __restrict__ a2f, const float* __restrict__ maxa2f,
                        const float* __restrict__ mask, float* __restrict__ h2){
  int i0 = blockIdx.x*8;
  int g = i0 / NB;
  int wv_id = threadIdx.x >> 6;
  int lane = threadIdx.x & 63;
  float mx = maxa2f[0];
  float a1v[8], m[8], acc0[8], acc1[8], dsum[8];
  #pragma unroll
  for (int r=0;r<8;++r){
    a1v[r]=a1f[i0+r]; m[r]=leaky(a1v[r]+mx);
    acc0[r]=0.f; acc1[r]=0.f; dsum[r]=0.f;
  }
  int jbase = g*NB;
  for (int c = wv_id*4; c < wv_id*4+4; ++c){
    int j = jbase + c*64 + lane;
    float a2v = a2f[j];
    float w[8];
    #pragma unroll
    for (int r=0;r<8;++r){
      float val = __expf(leaky(a1v[r]+a2v)-m[r]) * mask[(size_t)(i0+r)*Nn + j];
      w[r]=val; dsum[r]+=val;
    }
    const float* fp = ftf + (size_t)(jbase + c*64)*DMID;
    #pragma unroll 16
    for (int jj=0;jj<64;++jj){
      float f0 = fp[(size_t)jj*DMID + lane];
      float f1 = fp[(size_t)jj*DMID + 64 + lane];
      #pragma unroll
      for (int r=0;r<8;++r){
        float s = rdlane(w[r], jj);
        acc0[r] += s*f0; acc1[r] += s*f1;
      }
    }
  }
  __shared__ float s_acc[2][8][DMID];
  __shared__ float s_d[2][8];
  #pragma unroll
  for (int r=0;r<8;++r){
    float ds = wave_sum(dsum[r]);
    if (lane==0) s_d[wv_id][r] = ds;
    s_acc[wv_id][r][lane] = acc0[r];
    s_acc[wv_id][r][64+lane] = acc1[r];
  }
  __syncthreads();
  int t = threadIdx.x;
  #pragma unroll
  for (int r=0;r<8;++r){
    float tot = s_acc[0][r][t] + s_acc[1][r][t];
    float denom = s_d[0][r] + s_d[1][r] + EPSV;
    float o = tot/denom;
    o = o>0.f ? o : __expf(o)-1.f;
    h2[(size_t)(i0+r)*DMID + t] = o;
  }
}

// pooled = segment_sum(h2); out = relu(pooled@W1+b1)@W2 + b2
__global__ void k_pool(const float* __restrict__ h2, const float* __restrict__ W1,
                       const float* __restrict__ b1, const float* __restrict__ W2,
                       const float* __restrict__ b2, float* __restrict__ out){
  int gid = blockIdx.x;  // 12
  int d = threadIdx.x;   // 128
  float s = 0.f;
  for (int n=0;n<NB;++n) s += h2[(size_t)(gid*NB+n)*DMID + d];
  __shared__ float ps[DMID], ts[DMID];
  ps[d] = s; __syncthreads();
  float acc = b1[d];
  for (int k=0;k<DMID;++k) acc += ps[k]*W1[k*DMID+d];
  ts[d] = fmaxf(acc, 0.f); __syncthreads();
  if (d < 16){
    float o = b2[d];
    for (int k=0;k<DMID;++k) o += ts[k]*W2[k*16+d];
    out[gid*16+d] = o;
  }
}

extern "C" void kernel_launch(void* const* d_in, const int* in_sizes, int n_in,
                              void* d_out, int out_size, void* d_ws, size_t ws_size,
                              hipStream_t stream) {
  const float* x    = (const float*)d_in[0];
  const float* mask = (const float*)d_in[1];
  // d_in[2] = batch (int32) — structure known: g = n / 512
  const float* Wv   = (const float*)d_in[3];
  const float* bv   = (const float*)d_in[4];
  const float* W0   = (const float*)d_in[5];
  const float* al0  = (const float*)d_in[6];
  const float* ar0  = (const float*)d_in[7];
  const float* Wf   = (const float*)d_in[8];
  const float* alf  = (const float*)d_in[9];
  const float* arf  = (const float*)d_in[10];
  const float* W1   = (const float*)d_in[11];
  const float* b1   = (const float*)d_in[12];
  const float* W2   = (const float*)d_in[13];
  const float* b2   = (const float*)d_in[14];
  float* out = (float*)d_out;

  float* ws = (float*)d_ws;
  float* h      = ws;                    // 6144*128
  float* ft0    = h      + Nn*DMID;      // 6144*256
  float* h1     = ft0    + Nn*NH*DHID;   // 6144*256
  float* ftf    = h1     + Nn*NH*DHID;   // 6144*128
  float* h2     = ftf    + Nn*DMID;      // 6144*128
  float* a1arr  = h2     + Nn*DMID;      // 4*6144
  float* a2arr  = a1arr  + NH*Nn;        // 4*6144
  float* a1f    = a2arr  + NH*Nn;        // 6144
  float* a2f    = a1f    + Nn;           // 6144
  float* maxa2  = a2f    + Nn;           // 4
  float* maxa2f = maxa2  + NH;           // 1

  hipLaunchKernelGGL(k_fc1,   dim3(Nn/8), dim3(128), 0, stream, x, Wv, bv, h);
  hipLaunchKernelGGL(k_ft0,   dim3(Nn/8), dim3(256), 0, stream, h, W0, al0, ar0, ft0, a1arr, a2arr);
  hipLaunchKernelGGL(k_max,   dim3(NH),   dim3(256), 0, stream, a2arr, maxa2, Nn);
  hipLaunchKernelGGL(k_attn0, dim3(Nn/8), dim3(256), 0, stream, ft0, a1arr, a2arr, maxa2, mask, h1);
  hipLaunchKernelGGL(k_fcf,   dim3(Nn/8), dim3(128), 0, stream, h1, Wf, ftf);
  hipLaunchKernelGGL(k_dotsf, dim3(Nn/4), dim3(256), 0, stream, ftf, alf, arf, a1f, a2f);
  hipLaunchKernelGGL(k_max,   dim3(1),    dim3(256), 0, stream, a2f, maxa2f, Nn);
  hipLaunchKernelGGL(k_attnf, dim3(Nn/8), dim3(128), 0, stream, ftf, a1f, a2f, maxa2f, mask, h2);
  hipLaunchKernelGGL(k_pool,  dim3(NG),   dim3(128), 0, stream, h2, W1, b1, W2, b2, out);
}

// Round 2
// 159.162 us; speedup vs baseline: 1.1879x; 1.1879x over previous
//
#include <hip/hip_runtime.h>
#include <math.h>

#define Nn 6144
#define FIN 128
#define DMID 128
#define DHID 64
#define NH 4
#define NG 12
#define NB 512
#define ALPHA 0.2f
#define EPSV 1e-9f

typedef __bf16 bf16x8 __attribute__((ext_vector_type(8)));
typedef float f32x4 __attribute__((ext_vector_type(4)));

union BU { bf16x8 v; uint u[4]; uint4 q; };

__device__ __forceinline__ float leaky(float x){ return x > 0.f ? x : ALPHA*x; }
__device__ __forceinline__ float eluf(float x){ return x > 0.f ? x : __expf(x)-1.f; }
__device__ __forceinline__ unsigned short f2bf(float f){
  uint u = __float_as_uint(f);
  return (unsigned short)((u + 0x7FFFu + ((u>>16)&1u)) >> 16);
}
__device__ __forceinline__ uint encf(float f){
  uint u = __float_as_uint(f);
  return (u & 0x80000000u) ? ~u : (u | 0x80000000u);
}
__device__ __forceinline__ float decf(uint e){
  uint b = (e & 0x80000000u) ? (e & 0x7FFFFFFFu) : ~e;
  return __uint_as_float(b);
}
__device__ __forceinline__ float wave_sum(float v){
  #pragma unroll
  for (int off=32; off; off>>=1) v += __shfl_xor(v, off);
  return v;
}

// fused: h = relu(x@Wv+bv); ft0 = h@W0 (per head); dots a1/a2; atomic head-max of a2
// 8 rows per block, 256 threads
__global__ __launch_bounds__(256) void k_f1(
    const float* __restrict__ x, const float* __restrict__ Wv, const float* __restrict__ bv,
    const float* __restrict__ W0, const float* __restrict__ al0, const float* __restrict__ ar0,
    unsigned short* __restrict__ ftT, float* __restrict__ a1arr, float* __restrict__ a2arr,
    uint* __restrict__ encmax){
  int i0 = blockIdx.x*8;
  int t = threadIdx.x;
  __shared__ float xs[8][FIN];
  __shared__ float hs[8][DMID];
  for (int idx=t; idx<8*FIN; idx+=256) xs[idx>>7][idx&127] = x[(size_t)i0*FIN + idx];
  __syncthreads();
  {
    int ch = t & 127, rg = t >> 7;  // rows rg*4..rg*4+3
    float acc4[4];
    float bvv = bv[ch];
    #pragma unroll
    for (int q=0;q<4;++q) acc4[q]=bvv;
    #pragma unroll 4
    for (int k=0;k<FIN;++k){
      float wv = Wv[k*DMID + ch];
      #pragma unroll
      for (int q=0;q<4;++q) acc4[q] += xs[rg*4+q][k]*wv;
    }
    #pragma unroll
    for (int q=0;q<4;++q) hs[rg*4+q][ch] = fmaxf(acc4[q], 0.f);
  }
  __syncthreads();
  int hd = t>>6, d = t&63;
  float facc[8]={0,0,0,0,0,0,0,0};
  const float* wp = W0 + (size_t)hd*(DMID*DHID) + d;
  #pragma unroll 4
  for (int k=0;k<DMID;++k){
    float wval = wp[(size_t)k*DHID];
    #pragma unroll
    for (int r=0;r<8;++r) facc[r] += hs[r][k]*wval;
  }
  // store ftT (channel-major bf16): channel t, nodes i0..i0+7, one 16B store
  {
    uint4 st;
    st.x = (uint)f2bf(facc[0]) | ((uint)f2bf(facc[1])<<16);
    st.y = (uint)f2bf(facc[2]) | ((uint)f2bf(facc[3])<<16);
    st.z = (uint)f2bf(facc[4]) | ((uint)f2bf(facc[5])<<16);
    st.w = (uint)f2bf(facc[6]) | ((uint)f2bf(facc[7])<<16);
    *reinterpret_cast<uint4*>(ftT + (size_t)t*Nn + i0) = st;
  }
  float alv = al0[hd*DHID+d], arv = ar0[hd*DHID+d];
  float m8 = -INFINITY;
  #pragma unroll
  for (int r=0;r<8;++r){
    float s1 = wave_sum(facc[r]*alv);
    float s2 = wave_sum(facc[r]*arv);
    if (d==0){ a1arr[hd*Nn + i0+r] = s1; a2arr[hd*Nn + i0+r] = s2; }
    m8 = fmaxf(m8, s2);
  }
  if (d==0) atomicMax(&encmax[hd], encf(m8));
}

// attention layer0 (MFMA): 1 wave per (g, head, 16-row i-tile); out h1 f32 [6144][256]
__global__ __launch_bounds__(64) void k_attn0(
    const unsigned short* __restrict__ ftT, const float* __restrict__ a1arr,
    const float* __restrict__ a2arr, const uint* __restrict__ encmax,
    const float* __restrict__ mask, float* __restrict__ h1){
  int bid = blockIdx.x;          // 12*4*32
  int it = bid & 31;
  int hd = (bid>>5) & 3;
  int g  = bid >> 7;
  int i0 = g*NB + it*16;
  int jbase = g*NB;
  int lane = threadIdx.x;
  int row = lane & 15, kg = lane >> 4;
  float a1v = a1arr[hd*Nn + i0 + row];
  float mv = leaky(a1v + decf(encmax[hd]));
  f32x4 acc[4] = {{0,0,0,0},{0,0,0,0},{0,0,0,0},{0,0,0,0}};
  float dsum = 0.f;
  const float* mrow = mask + (size_t)(i0+row)*Nn;
  for (int js=0; js<NB; js+=32){
    int jc = jbase + js + kg*8;
    float4 mk0 = *reinterpret_cast<const float4*>(mrow + jc);
    float4 mk1 = *reinterpret_cast<const float4*>(mrow + jc + 4);
    float4 a20 = *reinterpret_cast<const float4*>(a2arr + hd*Nn + jc);
    float4 a21 = *reinterpret_cast<const float4*>(a2arr + hd*Nn + jc + 4);
    float wv[8];
    float a2l[8] = {a20.x,a20.y,a20.z,a20.w,a21.x,a21.y,a21.z,a21.w};
    float mkl[8] = {mk0.x,mk0.y,mk0.z,mk0.w,mk1.x,mk1.y,mk1.z,mk1.w};
    #pragma unroll
    for (int e=0;e<8;++e){
      float p = __expf(leaky(a1v + a2l[e]) - mv) * mkl[e];
      wv[e] = p; dsum += p;
    }
    BU A;
    #pragma unroll
    for (int q=0;q<4;++q) A.u[q] = (uint)f2bf(wv[2*q]) | ((uint)f2bf(wv[2*q+1])<<16);
    #pragma unroll
    for (int c=0;c<4;++c){
      BU B;
      B.q = *reinterpret_cast<const uint4*>(ftT + (size_t)(hd*DHID + c*16 + row)*Nn + jbase + js + kg*8);
      acc[c] = __builtin_amdgcn_mfma_f32_16x16x32_bf16(A.v, B.v, acc[c], 0, 0, 0);
    }
  }
  dsum += __shfl_xor(dsum, 16);
  dsum += __shfl_xor(dsum, 32);   // every lane: denom for row (lane&15)
  #pragma unroll
  for (int c=0;c<4;++c){
    #pragma unroll
    for (int reg=0;reg<4;++reg){
      float drow = __shfl(dsum, kg*4+reg) + EPSV;
      float o = eluf(acc[c][reg] / drow);
      h1[(size_t)(i0 + kg*4 + reg)*(NH*DHID) + hd*DHID + c*16 + row] = o;
    }
  }
}

// ftf = h1@Wf (f32 in regs -> ftfT bf16), dots a1f/a2f, atomic max
// 8 rows per block, 128 threads
__global__ __launch_bounds__(128) void k_fcf(
    const float* __restrict__ h1, const float* __restrict__ Wf,
    const float* __restrict__ alf, const float* __restrict__ arf,
    unsigned short* __restrict__ ftfT, float* __restrict__ a1f, float* __restrict__ a2f,
    uint* __restrict__ encmax){
  int i0 = blockIdx.x*8;
  int t = threadIdx.x;
  __shared__ float hsf[8][NH*DHID];
  __shared__ float dparts[2][8][2];
  for (int idx=t; idx<8*NH*DHID; idx+=128) hsf[idx>>8][idx&255] = h1[(size_t)i0*(NH*DHID) + idx];
  __syncthreads();
  float facc[8]={0,0,0,0,0,0,0,0};
  #pragma unroll 4
  for (int k=0;k<NH*DHID;++k){
    float wv = Wf[(size_t)k*DMID + t];
    #pragma unroll
    for (int r=0;r<8;++r) facc[r] += hsf[r][k]*wv;
  }
  {
    uint4 st;
    st.x = (uint)f2bf(facc[0]) | ((uint)f2bf(facc[1])<<16);
    st.y = (uint)f2bf(facc[2]) | ((uint)f2bf(facc[3])<<16);
    st.z = (uint)f2bf(facc[4]) | ((uint)f2bf(facc[5])<<16);
    st.w = (uint)f2bf(facc[6]) | ((uint)f2bf(facc[7])<<16);
    *reinterpret_cast<uint4*>(ftfT + (size_t)t*Nn + i0) = st;
  }
  int wid = t>>6, lane = t&63;
  float alv = alf[t], arv = arf[t];
  #pragma unroll
  for (int r=0;r<8;++r){
    float s1 = wave_sum(facc[r]*alv);
    float s2 = wave_sum(facc[r]*arv);
    if (lane==0){ dparts[wid][r][0]=s1; dparts[wid][r][1]=s2; }
  }
  __syncthreads();
  if (t < 8){
    float v1 = dparts[0][t][0] + dparts[1][t][0];
    float v2 = dparts[0][t][1] + dparts[1][t][1];
    a1f[i0+t] = v1; a2f[i0+t] = v2;
    float m = v2;
    #pragma unroll
    for (int off=4; off; off>>=1) m = fmaxf(m, __shfl_xor(m, off));
    if (t==0) atomicMax(&encmax[NH], encf(m));
  }
}

// final attention (MFMA) + fused pooling via atomicAdd: 1 wave per (g, 16-row i-tile)
__global__ __launch_bounds__(64) void k_attnf(
    const unsigned short* __restrict__ ftfT, const float* __restrict__ a1f,
    const float* __restrict__ a2f, const uint* __restrict__ encmax,
    const float* __restrict__ mask, float* __restrict__ pooled){
  int bid = blockIdx.x;          // 12*32
  int it = bid & 31;
  int g  = bid >> 5;
  int i0 = g*NB + it*16;
  int jbase = g*NB;
  int lane = threadIdx.x;
  int row = lane & 15, kg = lane >> 4;
  float a1v = a1f[i0 + row];
  float mv = leaky(a1v + decf(encmax[NH]));
  f32x4 acc[8];
  #pragma unroll
  for (int c=0;c<8;++c) acc[c] = (f32x4){0,0,0,0};
  float dsum = 0.f;
  const float* mrow = mask + (size_t)(i0+row)*Nn;
  for (int js=0; js<NB; js+=32){
    int jc = jbase + js + kg*8;
    float4 mk0 = *reinterpret_cast<const float4*>(mrow + jc);
    float4 mk1 = *reinterpret_cast<const float4*>(mrow + jc + 4);
    float4 a20 = *reinterpret_cast<const float4*>(a2f + jc);
    float4 a21 = *reinterpret_cast<const float4*>(a2f + jc + 4);
    float wv[8];
    float a2l[8] = {a20.x,a20.y,a20.z,a20.w,a21.x,a21.y,a21.z,a21.w};
    float mkl[8] = {mk0.x,mk0.y,mk0.z,mk0.w,mk1.x,mk1.y,mk1.z,mk1.w};
    #pragma unroll
    for (int e=0;e<8;++e){
      float p = __expf(leaky(a1v + a2l[e]) - mv) * mkl[e];
      wv[e] = p; dsum += p;
    }
    BU A;
    #pragma unroll
    for (int q=0;q<4;++q) A.u[q] = (uint)f2bf(wv[2*q]) | ((uint)f2bf(wv[2*q+1])<<16);
    #pragma unroll
    for (int c=0;c<8;++c){
      BU B;
      B.q = *reinterpret_cast<const uint4*>(ftfT + (size_t)(c*16 + row)*Nn + jbase + js + kg*8);
      acc[c] = __builtin_amdgcn_mfma_f32_16x16x32_bf16(A.v, B.v, acc[c], 0, 0, 0);
    }
  }
  dsum += __shfl_xor(dsum, 16);
  dsum += __shfl_xor(dsum, 32);
  #pragma unroll
  for (int c=0;c<8;++c){
    float psum = 0.f;
    #pragma unroll
    for (int reg=0;reg<4;++reg){
      float drow = __shfl(dsum, kg*4+reg) + EPSV;
      psum += eluf(acc[c][reg] / drow);
    }
    psum += __shfl_xor(psum, 16);
    psum += __shfl_xor(psum, 32);
    if (lane < 16) atomicAdd(&pooled[g*DMID + c*16 + lane], psum);
  }
}

// out = relu(pooled@W1+b1)@W2 + b2
__global__ __launch_bounds__(128) void k_mlp(
    const float* __restrict__ pooled, const float* __restrict__ W1, const float* __restrict__ b1,
    const float* __restrict__ W2, const float* __restrict__ b2, float* __restrict__ out){
  int g = blockIdx.x;
  int d = threadIdx.x;
  __shared__ float ps[DMID], ts[DMID];
  ps[d] = pooled[g*DMID + d];
  __syncthreads();
  float acc = b1[d];
  #pragma unroll 4
  for (int k=0;k<DMID;++k) acc += ps[k]*W1[k*DMID+d];
  ts[d] = fmaxf(acc, 0.f);
  __syncthreads();
  if (d < 16){
    float o = b2[d];
    #pragma unroll 4
    for (int k=0;k<DMID;++k) o += ts[k]*W2[k*16+d];
    out[g*16+d] = o;
  }
}

extern "C" void kernel_launch(void* const* d_in, const int* in_sizes, int n_in,
                              void* d_out, int out_size, void* d_ws, size_t ws_size,
                              hipStream_t stream) {
  const float* x    = (const float*)d_in[0];
  const float* mask = (const float*)d_in[1];
  const float* Wv   = (const float*)d_in[3];
  const float* bv   = (const float*)d_in[4];
  const float* W0   = (const float*)d_in[5];
  const float* al0  = (const float*)d_in[6];
  const float* ar0  = (const float*)d_in[7];
  const float* Wf   = (const float*)d_in[8];
  const float* alf  = (const float*)d_in[9];
  const float* arf  = (const float*)d_in[10];
  const float* W1   = (const float*)d_in[11];
  const float* b1   = (const float*)d_in[12];
  const float* W2   = (const float*)d_in[13];
  const float* b2   = (const float*)d_in[14];
  float* out = (float*)d_out;

  float* ws = (float*)d_ws;
  float* h1            = ws;                         // 6144*256       = 1572864
  unsigned short* ftT  = (unsigned short*)(ws + 1572864);   // 256*6144 u16 (786432 f)
  unsigned short* ftfT = (unsigned short*)(ws + 2359296);   // 128*6144 u16 (393216 f)
  float* a1arr = ws + 2752512;   // 4*6144
  float* a2arr = ws + 2777088;   // 4*6144
  float* a1f   = ws + 2801664;   // 6144
  float* a2f   = ws + 2807808;   // 6144
  float* pooled= ws + 2813952;   // 12*128
  uint*  encmax= (uint*)(ws + 2815488); // 5

  hipMemsetAsync(pooled, 0, (12*DMID + 5)*sizeof(float), stream);
  hipLaunchKernelGGL(k_f1,    dim3(Nn/8),      dim3(256), 0, stream,
                     x, Wv, bv, W0, al0, ar0, ftT, a1arr, a2arr, encmax);
  hipLaunchKernelGGL(k_attn0, dim3(NG*NH*32),  dim3(64),  0, stream,
                     ftT, a1arr, a2arr, encmax, mask, h1);
  hipLaunchKernelGGL(k_fcf,   dim3(Nn/8),      dim3(128), 0, stream,
                     h1, Wf, alf, arf, ftfT, a1f, a2f, encmax);
  hipLaunchKernelGGL(k_attnf, dim3(NG*32),     dim3(64),  0, stream,
                     ftfT, a1f, a2f, encmax, mask, pooled);
  hipLaunchKernelGGL(k_mlp,   dim3(NG),        dim3(128), 0, stream,
                     pooled, W1, b1, W2, b2, out);
}